// Round 5
// baseline (6510.316 us; speedup 1.0000x reference)
//
#include <hip/hip_runtime.h>

// Problem constants
#define BB 4
#define SS 32
#define CC 128
#define HH 16
#define WW 32
#define HID 128
#define DEPTH 2
#define CIN 256           // CC + HID
#define COUT 512          // 4*HID
#define K9 (CIN * 9)      // 2304
#define KH 1152           // k = cb*288 + tap*32 + c   (cb=cin>>5, c=cin&31)
#define HW (HH * WW)      // 512
#define MM (BB * HW)      // 2048
#define MBIG (SS * BB * HW) // 65536

// ---------------------------------------------------------------------------
// Weight split+transpose (channel-block-major, tap-inner k):
//   conv_w [DEPTH][COUT][CIN][3][3] ->
//     wtx [DEPTH][KH][COUT]  (cin <  CC : k = (cin>>5)*288 + tap*32 + (cin&31))
//     wth [DEPTH][KH][COUT]  (cin >= CC : same with cin-CC)
// ---------------------------------------------------------------------------
__global__ void transpose_w_kernel(const float* __restrict__ w,
                                   float* __restrict__ wtx, float* __restrict__ wth) {
    int idx = blockIdx.x * 256 + threadIdx.x;
    if (idx >= DEPTH * K9 * COUT) return;
    int n = idx % COUT;
    int k = (idx / COUT) % K9;
    int d = idx / (COUT * K9);
    int cin = k / 9, tap = k % 9;
    float v = w[(((long)(d * COUT + n) * CIN + cin) * 9) + tap];
    if (cin < CC) {
        int kn = ((cin >> 5) * 9 + tap) * 32 + (cin & 31);
        wtx[((long)d * KH + kn) * COUT + n] = v;
    } else {
        int ch = cin - CC;
        int kn = ((ch >> 5) * 9 + tap) * 32 + (ch & 31);
        wth[((long)d * KH + kn) * COUT + n] = v;
    }
}

// ---------------------------------------------------------------------------
// Broadcast init_h/init_c[d] into [B][HID][HW] state buffers
// ---------------------------------------------------------------------------
__global__ void init_state_kernel(const float* __restrict__ ih, const float* __restrict__ ic,
                                  float* __restrict__ h, float* __restrict__ c, int d) {
    int idx = blockIdx.x * 256 + threadIdx.x;   // B*HID*HW = 262144
    int hid = (idx >> 9) & (HID - 1);
    h[idx] = ih[d * HID + hid];
    c[idx] = ic[d * HID + hid];
}

// ---------------------------------------------------------------------------
// Big feed-forward GEMM over ALL timesteps (x-part of the conv).
// Tile 128x128 (m-tile = 4 image rows of one image), 256 threads, 8x8 acc.
// Per 32-channel block: image slab (32ch x 6row x 36col, zero halo) loaded to
// LDS ONCE, then 9 taps read shifted slab — no global refetch per tap, no
// bounds checks in the hot loop. grid = (512, 4).
// ---------------------------------------------------------------------------
__launch_bounds__(256)
__global__ void big_gemm_kernel(const float* __restrict__ xin, long strideS, long strideB,
                                const float* __restrict__ wt,   // [KH][COUT]
                                float* __restrict__ zx) {
    __shared__ float slab[32][6][36];   // 27.6 KB
    __shared__ __align__(16) float Bs[32][128];  // 16 KB

    const int m0 = blockIdx.x * 128;
    const int n0 = blockIdx.y * 128;
    const int tid = threadIdx.x;
    const int tx = tid & 15;        // m
    const int ty = tid >> 4;        // n
    const int sb  = m0 >> 9;        // (s*B + b) image index
    const int hw0 = m0 & 511;
    const int y0  = hw0 >> 5;       // first image row of this m-tile
    const float* img = xin + (long)(sb >> 2) * strideS + (long)(sb & 3) * strideB;

    float acc[8][8] = {};
    const int ra0 = tx >> 3;        // local row 0..1
    const int xb  = (tx & 7) * 4;   // x base 0..28

    for (int cb = 0; cb < 4; ++cb) {
        __syncthreads();            // previous tap's FMA done before slab overwrite
        // load slab: 32ch x 6 rows x 36 cols (zero halo), 6912 elems, 27/thread
        #pragma unroll
        for (int i = 0; i < 27; ++i) {
            int idx = i * 256 + tid;
            int ch  = idx / 216;
            int rem = idx - ch * 216;
            int row = rem / 36;
            int col = rem - row * 36;
            int yy = y0 + row - 1;
            int xx = col - 1;
            float v = 0.f;
            if ((unsigned)yy < (unsigned)HH && (unsigned)xx < (unsigned)WW)
                v = img[(cb * 32 + ch) * HW + yy * WW + xx];
            slab[ch][row][col] = v;
        }
        for (int tap = 0; tap < 9; ++tap) {
            __syncthreads();        // Bs consumed (and slab visible on tap 0)
            const int kb = cb * 288 + tap * 32;
            #pragma unroll
            for (int i = 0; i < 16; ++i) {
                int idx = i * 256 + tid;
                int kk = idx >> 7;
                int n  = idx & 127;
                Bs[kk][n] = wt[(long)(kb + kk) * COUT + n0 + n];
            }
            __syncthreads();
            const int ry = tap / 3;         // slab row offset
            const int rx = tap - ry * 3;    // slab col offset
            #pragma unroll
            for (int kk = 0; kk < 32; ++kk) {
                float av[8], bv[8];
                #pragma unroll
                for (int i = 0; i < 4; ++i) {
                    av[i]     = slab[kk][ra0 + ry][xb + rx + i];
                    av[4 + i] = slab[kk][ra0 + 2 + ry][xb + rx + i];
                }
                float4 b0 = *(const float4*)&Bs[kk][ty * 4];
                float4 b1 = *(const float4*)&Bs[kk][64 + ty * 4];
                bv[0] = b0.x; bv[1] = b0.y; bv[2] = b0.z; bv[3] = b0.w;
                bv[4] = b1.x; bv[5] = b1.y; bv[6] = b1.z; bv[7] = b1.w;
                #pragma unroll
                for (int i = 0; i < 8; ++i)
                    #pragma unroll
                    for (int j = 0; j < 8; ++j)
                        acc[i][j] += av[i] * bv[j];
            }
        }
    }

    const long outbase = (long)sb * COUT * HW;
    #pragma unroll
    for (int j = 0; j < 8; ++j) {
        int n = n0 + ((j < 4) ? (ty * 4 + j) : (64 + ty * 4 + j - 4));
        float4 v0 = make_float4(acc[0][j], acc[1][j], acc[2][j], acc[3][j]);
        float4 v1 = make_float4(acc[4][j], acc[5][j], acc[6][j], acc[7][j]);
        *(float4*)&zx[outbase + (long)n * HW + hw0 + tx * 4]      = v0;
        *(float4*)&zx[outbase + (long)n * HW + hw0 + 64 + tx * 4] = v1;
    }
}

// ---------------------------------------------------------------------------
// Per-step recurrent GEMM (h-part, K=1152), split-K=4: chunk kc == one
// 32-channel block (288 k). Tile 64x64 (2 image rows), 4x4 acc. Slab
// (32ch x 4row x 36col) loaded once per wg. grid = (32, 8, 4).
// ---------------------------------------------------------------------------
__launch_bounds__(256)
__global__ void step_gemm_h(const float* __restrict__ hprev,   // [B][HID][HW]
                            const float* __restrict__ wth,     // [KH][COUT]
                            float* __restrict__ part) {
    __shared__ float slab[32][4][36];   // 18 KB
    __shared__ __align__(16) float Bs[32][64];   // 8 KB

    const int m0 = blockIdx.x * 64;
    const int n0 = blockIdx.y * 64;
    const int kc = blockIdx.z;          // channel block
    const int tid = threadIdx.x;
    const int tx = tid & 15;
    const int ty = tid >> 4;
    const int b   = m0 >> 9;
    const int hw0 = m0 & 511;
    const int y0  = hw0 >> 5;           // first image row (2-row tile)

    float acc[4][4] = {};
    const int ra0 = tx >> 3;            // local row 0..1
    const int xb  = (tx & 7) * 4;

    // load slab: 32ch x 4 rows x 36 cols, 4608 elems, 18/thread
    #pragma unroll
    for (int i = 0; i < 18; ++i) {
        int idx = i * 256 + tid;
        int ch  = idx / 144;
        int rem = idx - ch * 144;
        int row = rem / 36;
        int col = rem - row * 36;
        int yy = y0 + row - 1;
        int xx = col - 1;
        float v = 0.f;
        if ((unsigned)yy < (unsigned)HH && (unsigned)xx < (unsigned)WW)
            v = hprev[((long)(b * HID + kc * 32 + ch)) * HW + yy * WW + xx];
        slab[ch][row][col] = v;
    }

    for (int tap = 0; tap < 9; ++tap) {
        if (tap) __syncthreads();       // Bs consumed
        const int kb = kc * 288 + tap * 32;
        #pragma unroll
        for (int i = 0; i < 8; ++i) {
            int idx = i * 256 + tid;
            int kk = idx >> 6;
            int n  = idx & 63;
            Bs[kk][n] = wth[(long)(kb + kk) * COUT + n0 + n];
        }
        __syncthreads();                // Bs ready (and slab on tap 0)
        const int ry = tap / 3;
        const int rx = tap - ry * 3;
        #pragma unroll
        for (int kk = 0; kk < 32; ++kk) {
            float av[4];
            #pragma unroll
            for (int i = 0; i < 4; ++i)
                av[i] = slab[kk][ra0 + ry][xb + rx + i];
            float4 bq = *(const float4*)&Bs[kk][ty * 4];
            float bv[4] = {bq.x, bq.y, bq.z, bq.w};
            #pragma unroll
            for (int i = 0; i < 4; ++i)
                #pragma unroll
                for (int j = 0; j < 4; ++j)
                    acc[i][j] += av[i] * bv[j];
        }
    }

    const long pbase = ((long)kc * BB) * COUT * HW;
    const int hw = hw0 + tx * 4;
    #pragma unroll
    for (int j = 0; j < 4; ++j) {
        int n = n0 + ty * 4 + j;
        float4 v = make_float4(acc[0][j], acc[1][j], acc[2][j], acc[3][j]);
        *(float4*)&part[pbase + ((long)b * COUT + n) * HW + hw] = v;
    }
}

// ---------------------------------------------------------------------------
// Fused split-K reduce + zx + bias + LSTM cell update.
// ---------------------------------------------------------------------------
__global__ void lstm_gate_fused(const float* __restrict__ part,  // [4][B][COUT][HW]
                                const float* __restrict__ zx,    // [B][COUT][HW] (step slice)
                                const float* __restrict__ bias,  // [COUT]
                                float* __restrict__ h, float* __restrict__ c,
                                float* __restrict__ seq_out) {
    const long PSTR = (long)BB * COUT * HW;
    int idx = blockIdx.x * 256 + threadIdx.x;     // over B*HID*HW = 262144
    int hw  = idx & 511;
    int hid = (idx >> 9) & (HID - 1);
    int b   = idx >> 16;
    long base = (long)b * COUT * HW + hw;
    float g[4];
    #pragma unroll
    for (int gi = 0; gi < 4; ++gi) {
        long o = base + (long)(hid + gi * HID) * HW;
        float v = zx[o] + bias[hid + gi * HID];
        v += part[o];
        v += part[o + PSTR];
        v += part[o + 2 * PSTR];
        v += part[o + 3 * PSTR];
        g[gi] = v;
    }
    float si = 1.f / (1.f + expf(-g[0]));
    float sf = 1.f / (1.f + expf(-g[1]));
    float so = 1.f / (1.f + expf(-g[3]));
    float cs = sf * c[idx] + si * tanhf(g[2]);
    float hs = so * tanhf(cs);
    c[idx] = cs;
    h[idx] = hs;
    seq_out[idx] = hs;
}

// ---------------------------------------------------------------------------
// Mean pool over HW: seq [S][B][HID][HW] -> pooled [S*B*HID]
// ---------------------------------------------------------------------------
__global__ void pool_kernel(const float* __restrict__ seq, float* __restrict__ pooled) {
    int row  = blockIdx.x * 4 + (threadIdx.x >> 6);
    int lane = threadIdx.x & 63;
    const float* p = seq + (long)row * HW;
    float sum = 0.f;
    #pragma unroll
    for (int i = 0; i < HW / 64; ++i) sum += p[lane + i * 64];
    #pragma unroll
    for (int off = 32; off; off >>= 1) sum += __shfl_down(sum, off);
    if (lane == 0) pooled[row] = sum * (1.f / HW);
}

// ---------------------------------------------------------------------------
// FC + ReLU + two scalar heads.
// ---------------------------------------------------------------------------
__global__ void head_kernel(const float* __restrict__ pooled,
                            const float* __restrict__ fc_w, const float* __restrict__ fc_b,
                            const float* __restrict__ fco_w, const float* __restrict__ fco_b,
                            const float* __restrict__ fca_w, const float* __restrict__ fca_b,
                            float* __restrict__ out) {
    int bs = blockIdx.x;          // b*S + s
    int b  = bs / SS;
    int s  = bs % SS;
    int j  = threadIdx.x;
    const float* prow = pooled + (long)(s * BB + b) * HID;
    float acc = fc_b[j];
    #pragma unroll 4
    for (int k = 0; k < HID; ++k) acc += fc_w[j * HID + k] * prow[k];
    float f = fmaxf(acc, 0.f);
    __shared__ float ro[128], ra[128];
    ro[j] = f * fco_w[j];
    ra[j] = f * fca_w[j];
    __syncthreads();
    for (int off = 64; off; off >>= 1) {
        if (j < off) { ro[j] += ro[j + off]; ra[j] += ra[j + off]; }
        __syncthreads();
    }
    if (j == 0) {
        out[bs]           = ro[0] + fco_b[0];
        out[BB * SS + bs] = ra[0] + fca_b[0];
    }
}

// ---------------------------------------------------------------------------
extern "C" void kernel_launch(void* const* d_in, const int* in_sizes, int n_in,
                              void* d_out, int out_size, void* d_ws, size_t ws_size,
                              hipStream_t stream) {
    const float* x      = (const float*)d_in[0];
    const float* conv_w = (const float*)d_in[1];
    const float* conv_b = (const float*)d_in[2];
    const float* init_h = (const float*)d_in[3];
    const float* init_c = (const float*)d_in[4];
    const float* fc_w   = (const float*)d_in[5];
    const float* fc_b   = (const float*)d_in[6];
    const float* fco_w  = (const float*)d_in[7];
    const float* fco_b  = (const float*)d_in[8];
    const float* fca_w  = (const float*)d_in[9];
    const float* fca_b  = (const float*)d_in[10];
    float* out = (float*)d_out;

    // Workspace carve-up (floats), total ~49.0M floats = ~196 MB.
    float* ws     = (float*)d_ws;
    float* wtx    = ws;                                   // DEPTH*KH*COUT = 1,179,648
    float* wth    = wtx  + (long)DEPTH * KH * COUT;       // 1,179,648
    float* zx     = wth  + (long)DEPTH * KH * COUT;       // S*B*COUT*HW  = 33,554,432
    float* seq    = zx   + (long)SS * BB * COUT * HW;     // S*B*HID*HW   = 8,388,608
    float* part   = seq  + (long)SS * BB * HID * HW;      // 4*B*COUT*HW  = 4,194,304
    float* hbuf   = part + (long)4 * BB * COUT * HW;      // 262,144
    float* cbuf   = hbuf + (long)BB * HID * HW;           // 262,144
    float* pooled = cbuf + (long)BB * HID * HW;           // 16,384

    transpose_w_kernel<<<(DEPTH * K9 * COUT + 255) / 256, 256, 0, stream>>>(conv_w, wtx, wth);

    const long ZSTEP = (long)BB * COUT * HW;
    const long QSTEP = (long)BB * HID * HW;

    for (int d = 0; d < DEPTH; ++d) {
        // x-part of the conv for ALL timesteps: one big parallel GEMM
        if (d == 0)
            big_gemm_kernel<<<dim3(MBIG / 128, COUT / 128), 256, 0, stream>>>(
                x, (long)CC * HW, (long)SS * CC * HW, wtx, zx);
        else
            big_gemm_kernel<<<dim3(MBIG / 128, COUT / 128), 256, 0, stream>>>(
                seq, (long)BB * HID * HW, (long)HID * HW, wtx + (long)KH * COUT, zx);

        init_state_kernel<<<(BB * HID * HW) / 256, 256, 0, stream>>>(init_h, init_c, hbuf, cbuf, d);

        const float* wth_d  = wth + (long)d * KH * COUT;
        const float* bias_d = conv_b + d * COUT;
        for (int s = 0; s < SS; ++s) {
            step_gemm_h<<<dim3(MM / 64, COUT / 64, 4), 256, 0, stream>>>(hbuf, wth_d, part);
            lstm_gate_fused<<<(BB * HID * HW) / 256, 256, 0, stream>>>(
                part, zx + (long)s * ZSTEP, bias_d, hbuf, cbuf, seq + (long)s * QSTEP);
        }
    }
    pool_kernel<<<(SS * BB * HID) / 4, 256, 0, stream>>>(seq, pooled);
    head_kernel<<<BB * SS, 128, 0, stream>>>(pooled, fc_w, fc_b, fco_w, fco_b, fca_w, fca_b, out);
}

// Round 6
// 4662.881 us; speedup vs baseline: 1.3962x; 1.3962x over previous
//
#include <hip/hip_runtime.h>

// Problem constants
#define BB 4
#define SS 32
#define CC 128
#define HH 16
#define WW 32
#define HID 128
#define DEPTH 2
#define CIN 256           // CC + HID
#define COUT 512          // 4*HID
#define K9 (CIN * 9)      // 2304
#define KH 1152           // tap-major: k = tap*128 + cin
#define HW (HH * WW)      // 512
#define MM (BB * HW)      // 2048
#define MBIG (SS * BB * HW) // 65536

typedef __attribute__((ext_vector_type(4))) float f32x4;
typedef __attribute__((ext_vector_type(8))) short bf16x8;

static __device__ __forceinline__ unsigned short f2bf(float f) {
    union { float f; unsigned u; } v; v.f = f;
    unsigned r = v.u + 0x7FFF + ((v.u >> 16) & 1);   // RNE
    return (unsigned short)(r >> 16);
}
static __device__ __forceinline__ float bf2f(unsigned short h) {
    union { float f; unsigned u; } v; v.u = ((unsigned)h) << 16; return v.f;
}

// ---------------------------------------------------------------------------
// Weight split+transpose (tap-major k = tap*128 + ch):
//   conv_w [DEPTH][COUT][CIN][3][3] ->
//     wtx_hl [DEPTH][KH][COUT] uint  (cin <  CC : bf16 hi | lo<<16)
//     wth    [DEPTH][KH][COUT] float (cin >= CC : fp32 for step path)
// ---------------------------------------------------------------------------
__global__ void transpose_w_kernel(const float* __restrict__ w,
                                   unsigned int* __restrict__ wtx_hl,
                                   float* __restrict__ wth) {
    int idx = blockIdx.x * 256 + threadIdx.x;
    if (idx >= DEPTH * K9 * COUT) return;
    int n = idx % COUT;
    int k = (idx / COUT) % K9;
    int d = idx / (COUT * K9);
    int cin = k / 9, tap = k % 9;
    float v = w[(((long)(d * COUT + n) * CIN + cin) * 9) + tap];
    if (cin < CC) {
        unsigned short hi = f2bf(v);
        unsigned short lo = f2bf(v - bf2f(hi));
        wtx_hl[((long)d * KH + (tap * CC + cin)) * COUT + n] =
            (unsigned)hi | ((unsigned)lo << 16);
    } else {
        wth[((long)d * KH + (tap * HID + (cin - CC))) * COUT + n] = v;
    }
}

// ---------------------------------------------------------------------------
// Broadcast init_h/init_c[d] into [B][HID][HW] state buffers
// ---------------------------------------------------------------------------
__global__ void init_state_kernel(const float* __restrict__ ih, const float* __restrict__ ic,
                                  float* __restrict__ h, float* __restrict__ c, int d) {
    int idx = blockIdx.x * 256 + threadIdx.x;   // B*HID*HW = 262144
    int hid = (idx >> 9) & (HID - 1);
    h[idx] = ih[d * HID + hid];
    c[idx] = ic[d * HID + hid];
}

// ---------------------------------------------------------------------------
// Big feed-forward GEMM over ALL timesteps — MFMA bf16x3 (hi/lo split).
// Tile 128x128, 4 waves (2x2 of 64x64), BK=32 tap-major, LDS frag layout
// [row][k] ushort stride 36 (conflict-free b128 reads).
// grid = (512, 4), 256 threads.
// ---------------------------------------------------------------------------
__launch_bounds__(256)
__global__ void big_gemm_mfma(const float* __restrict__ xin, long strideS, long strideB,
                              const unsigned int* __restrict__ wt_hl,  // [KH][COUT]
                              float* __restrict__ zx) {
    __shared__ unsigned short Ah[128][36], Al[128][36];   // 9.2 KB each
    __shared__ unsigned short Bh[128][36], Bl[128][36];

    const int m0 = blockIdx.x * 128;
    const int n0 = blockIdx.y * 128;
    const int tid  = threadIdx.x;
    const int lane = tid & 63;
    const int wid  = tid >> 6;          // 4 waves
    const int wm = (wid >> 1) * 64;     // wave m offset in tile
    const int wn = (wid & 1) * 64;      // wave n offset
    const int sb  = m0 >> 9;            // image index (s*B+b)
    const int hw0 = m0 & 511;
    const float* img = xin + (long)(sb >> 2) * strideS + (long)(sb & 3) * strideB;

    f32x4 acc[4][4];
    #pragma unroll
    for (int i = 0; i < 4; ++i)
        #pragma unroll
        for (int j = 0; j < 4; ++j)
            acc[i][j] = (f32x4){0.f, 0.f, 0.f, 0.f};

    for (int k0 = 0; k0 < KH; k0 += 32) {
        const int tap = k0 >> 7;            // uniform per chunk
        const int c0  = k0 & 127;
        const int ky  = tap / 3 - 1;
        const int kx  = tap - (tap / 3) * 3 - 1;
        // --- stage A: im2col gather -> hi/lo bf16 ---
        #pragma unroll
        for (int i = 0; i < 16; ++i) {
            int idx = i * 256 + tid;        // 0..4095
            int kk = idx >> 7;              // 0..31
            int m  = idx & 127;
            int hw = hw0 + m;
            int yy = (hw >> 5) + ky;
            int xq = (hw & 31) + kx;
            float v = 0.f;
            if ((unsigned)yy < (unsigned)HH && (unsigned)xq < (unsigned)WW)
                v = img[(c0 + kk) * HW + yy * WW + xq];
            unsigned short h = f2bf(v);
            Ah[m][kk] = h;
            Al[m][kk] = f2bf(v - bf2f(h));
        }
        // --- stage B: packed hi|lo uint, coalesced ---
        #pragma unroll
        for (int i = 0; i < 16; ++i) {
            int idx = i * 256 + tid;
            int kk = idx >> 7;
            int n  = idx & 127;
            unsigned p = wt_hl[(long)(k0 + kk) * COUT + n0 + n];
            Bh[n][kk] = (unsigned short)p;
            Bl[n][kk] = (unsigned short)(p >> 16);
        }
        __syncthreads();

        // --- fragments: row = lane&15, k = 8*(lane>>4)+j ---
        const int fr = lane & 15;
        const int kq = (lane >> 4) * 8;
        bf16x8 ah[4], al[4], bh[4], bl[4];
        #pragma unroll
        for (int f = 0; f < 4; ++f) {
            ah[f] = *(const bf16x8*)&Ah[wm + f * 16 + fr][kq];
            al[f] = *(const bf16x8*)&Al[wm + f * 16 + fr][kq];
            bh[f] = *(const bf16x8*)&Bh[wn + f * 16 + fr][kq];
            bl[f] = *(const bf16x8*)&Bl[wn + f * 16 + fr][kq];
        }
        #pragma unroll
        for (int fm = 0; fm < 4; ++fm)
            #pragma unroll
            for (int fn = 0; fn < 4; ++fn) {
                acc[fm][fn] = __builtin_amdgcn_mfma_f32_16x16x32_bf16(ah[fm], bh[fn], acc[fm][fn], 0, 0, 0);
                acc[fm][fn] = __builtin_amdgcn_mfma_f32_16x16x32_bf16(ah[fm], bl[fn], acc[fm][fn], 0, 0, 0);
                acc[fm][fn] = __builtin_amdgcn_mfma_f32_16x16x32_bf16(al[fm], bh[fn], acc[fm][fn], 0, 0, 0);
            }
        __syncthreads();
    }

    // store: D row(m) = 4*(lane>>4)+r, col(n) = lane&15 -> float4 along m
    const long outbase = (long)sb * COUT * HW;
    const int rm = (lane >> 4) * 4;
    const int cn = lane & 15;
    #pragma unroll
    for (int fm = 0; fm < 4; ++fm)
        #pragma unroll
        for (int fn = 0; fn < 4; ++fn) {
            int m = hw0 + wm + fm * 16 + rm;
            int n = n0 + wn + fn * 16 + cn;
            *(float4*)&zx[outbase + (long)n * HW + m] = *(float4*)&acc[fm][fn];
        }
}

// ---------------------------------------------------------------------------
// Per-step recurrent GEMM (h-part only, K=1152), split-K=4 (288 each).
// Tile 64x64, BK=32, 256 threads, 4x4 acc, register-prefetch double buffer,
// tap-major k, float4 stores. grid = (32,8,4).  [round-4 proven version]
// ---------------------------------------------------------------------------
__global__ void step_gemm_h(const float* __restrict__ hprev,   // [B][HID][HW]
                            const float* __restrict__ wth,     // [KH][COUT] tap-major
                            float* __restrict__ part) {
    __shared__ __align__(16) float As[32][64];
    __shared__ __align__(16) float Bs[32][64];

    const int m0 = blockIdx.x * 64;
    const int n0 = blockIdx.y * 64;
    const int kc = blockIdx.z;
    const int tid = threadIdx.x;
    const int tx = tid & 15;
    const int ty = tid >> 4;

    float acc[4][4] = {};
    float pa[8], pb[8];

    auto loadA = [&](int k0) {
        const int tap = k0 >> 7;
        const int c0  = k0 & 127;
        const int ky  = tap / 3 - 1;
        const int kx  = tap - (tap / 3) * 3 - 1;
        #pragma unroll
        for (int i = 0; i < 8; ++i) {
            int idx = i * 256 + tid;
            int kk = idx >> 6;
            int m  = idx & 63;
            int mm = m0 + m;
            int b  = mm >> 9;
            int yy = ((mm >> 5) & 15) + ky;
            int xq = (mm & 31) + kx;
            float v = 0.f;
            if ((unsigned)yy < (unsigned)HH && (unsigned)xq < (unsigned)WW)
                v = hprev[((long)(b * HID + c0 + kk)) * HW + yy * WW + xq];
            pa[i] = v;
        }
    };
    auto loadB = [&](int k0) {
        #pragma unroll
        for (int i = 0; i < 8; ++i) {
            int idx = i * 256 + tid;
            int kk = idx >> 6;
            int n  = idx & 63;
            pb[i] = wth[(long)(k0 + kk) * COUT + n0 + n];
        }
    };
    auto commit = [&]() {
        #pragma unroll
        for (int i = 0; i < 8; ++i) {
            int idx = i * 256 + tid;
            int kk = idx >> 6;
            int mn = idx & 63;
            As[kk][mn] = pa[i];
            Bs[kk][mn] = pb[i];
        }
    };

    const int kbase = kc * 288;
    loadA(kbase); loadB(kbase);
    commit();
    __syncthreads();

    for (int k0i = 0; k0i < 288; k0i += 32) {
        const bool more = (k0i + 32 < 288);
        if (more) { loadA(kbase + k0i + 32); loadB(kbase + k0i + 32); }

        #pragma unroll
        for (int kk = 0; kk < 32; ++kk) {
            float4 a = *(const float4*)&As[kk][tx * 4];
            float4 b = *(const float4*)&Bs[kk][ty * 4];
            acc[0][0] += a.x * b.x; acc[0][1] += a.x * b.y; acc[0][2] += a.x * b.z; acc[0][3] += a.x * b.w;
            acc[1][0] += a.y * b.x; acc[1][1] += a.y * b.y; acc[1][2] += a.y * b.z; acc[1][3] += a.y * b.w;
            acc[2][0] += a.z * b.x; acc[2][1] += a.z * b.y; acc[2][2] += a.z * b.z; acc[2][3] += a.z * b.w;
            acc[3][0] += a.w * b.x; acc[3][1] += a.w * b.y; acc[3][2] += a.w * b.z; acc[3][3] += a.w * b.w;
        }
        __syncthreads();
        if (more) {
            commit();
            __syncthreads();
        }
    }

    const long pbase = ((long)kc * BB) * COUT * HW;
    const int mm = m0 + tx * 4;
    const int b  = mm >> 9;
    const int hw = mm & 511;
    #pragma unroll
    for (int j = 0; j < 4; ++j) {
        int n = n0 + ty * 4 + j;
        float4 v = make_float4(acc[0][j], acc[1][j], acc[2][j], acc[3][j]);
        *(float4*)&part[pbase + ((long)b * COUT + n) * HW + hw] = v;
    }
}

// ---------------------------------------------------------------------------
// Fused split-K reduce + zx + bias + LSTM cell update.
// ---------------------------------------------------------------------------
__global__ void lstm_gate_fused(const float* __restrict__ part,  // [4][B][COUT][HW]
                                const float* __restrict__ zx,    // [B][COUT][HW] (step slice)
                                const float* __restrict__ bias,  // [COUT]
                                float* __restrict__ h, float* __restrict__ c,
                                float* __restrict__ seq_out) {
    const long PSTR = (long)BB * COUT * HW;
    int idx = blockIdx.x * 256 + threadIdx.x;     // over B*HID*HW = 262144
    int hw  = idx & 511;
    int hid = (idx >> 9) & (HID - 1);
    int b   = idx >> 16;
    long base = (long)b * COUT * HW + hw;
    float g[4];
    #pragma unroll
    for (int gi = 0; gi < 4; ++gi) {
        long o = base + (long)(hid + gi * HID) * HW;
        float v = zx[o] + bias[hid + gi * HID];
        v += part[o];
        v += part[o + PSTR];
        v += part[o + 2 * PSTR];
        v += part[o + 3 * PSTR];
        g[gi] = v;
    }
    float si = 1.f / (1.f + expf(-g[0]));
    float sf = 1.f / (1.f + expf(-g[1]));
    float so = 1.f / (1.f + expf(-g[3]));
    float cs = sf * c[idx] + si * tanhf(g[2]);
    float hs = so * tanhf(cs);
    c[idx] = cs;
    h[idx] = hs;
    seq_out[idx] = hs;
}

// ---------------------------------------------------------------------------
// Mean pool over HW: seq [S][B][HID][HW] -> pooled [S*B*HID]
// ---------------------------------------------------------------------------
__global__ void pool_kernel(const float* __restrict__ seq, float* __restrict__ pooled) {
    int row  = blockIdx.x * 4 + (threadIdx.x >> 6);
    int lane = threadIdx.x & 63;
    const float* p = seq + (long)row * HW;
    float sum = 0.f;
    #pragma unroll
    for (int i = 0; i < HW / 64; ++i) sum += p[lane + i * 64];
    #pragma unroll
    for (int off = 32; off; off >>= 1) sum += __shfl_down(sum, off);
    if (lane == 0) pooled[row] = sum * (1.f / HW);
}

// ---------------------------------------------------------------------------
// FC + ReLU + two scalar heads.
// ---------------------------------------------------------------------------
__global__ void head_kernel(const float* __restrict__ pooled,
                            const float* __restrict__ fc_w, const float* __restrict__ fc_b,
                            const float* __restrict__ fco_w, const float* __restrict__ fco_b,
                            const float* __restrict__ fca_w, const float* __restrict__ fca_b,
                            float* __restrict__ out) {
    int bs = blockIdx.x;          // b*S + s
    int b  = bs / SS;
    int s  = bs % SS;
    int j  = threadIdx.x;
    const float* prow = pooled + (long)(s * BB + b) * HID;
    float acc = fc_b[j];
    #pragma unroll 4
    for (int k = 0; k < HID; ++k) acc += fc_w[j * HID + k] * prow[k];
    float f = fmaxf(acc, 0.f);
    __shared__ float ro[128], ra[128];
    ro[j] = f * fco_w[j];
    ra[j] = f * fca_w[j];
    __syncthreads();
    for (int off = 64; off; off >>= 1) {
        if (j < off) { ro[j] += ro[j + off]; ra[j] += ra[j + off]; }
        __syncthreads();
    }
    if (j == 0) {
        out[bs]           = ro[0] + fco_b[0];
        out[BB * SS + bs] = ra[0] + fca_b[0];
    }
}

// ---------------------------------------------------------------------------
extern "C" void kernel_launch(void* const* d_in, const int* in_sizes, int n_in,
                              void* d_out, int out_size, void* d_ws, size_t ws_size,
                              hipStream_t stream) {
    const float* x      = (const float*)d_in[0];
    const float* conv_w = (const float*)d_in[1];
    const float* conv_b = (const float*)d_in[2];
    const float* init_h = (const float*)d_in[3];
    const float* init_c = (const float*)d_in[4];
    const float* fc_w   = (const float*)d_in[5];
    const float* fc_b   = (const float*)d_in[6];
    const float* fco_w  = (const float*)d_in[7];
    const float* fco_b  = (const float*)d_in[8];
    const float* fca_w  = (const float*)d_in[9];
    const float* fca_b  = (const float*)d_in[10];
    float* out = (float*)d_out;

    // Workspace carve-up (floats/uints, 4B units). Total ~49.0M = ~196 MB.
    float* ws     = (float*)d_ws;
    unsigned int* wtx_hl = (unsigned int*)ws;             // DEPTH*KH*COUT = 1,179,648
    float* wth    = ws   + (long)DEPTH * KH * COUT;       // 1,179,648
    float* zx     = wth  + (long)DEPTH * KH * COUT;       // S*B*COUT*HW  = 33,554,432
    float* seq    = zx   + (long)SS * BB * COUT * HW;     // S*B*HID*HW   = 8,388,608
    float* part   = seq  + (long)SS * BB * HID * HW;      // 4*B*COUT*HW  = 4,194,304
    float* hbuf   = part + (long)4 * BB * COUT * HW;      // 262,144
    float* cbuf   = hbuf + (long)BB * HID * HW;           // 262,144
    float* pooled = cbuf + (long)BB * HID * HW;           // 16,384

    transpose_w_kernel<<<(DEPTH * K9 * COUT + 255) / 256, 256, 0, stream>>>(conv_w, wtx_hl, wth);

    const long ZSTEP = (long)BB * COUT * HW;
    const long QSTEP = (long)BB * HID * HW;

    for (int d = 0; d < DEPTH; ++d) {
        // x-part of the conv for ALL timesteps: one big parallel MFMA GEMM
        if (d == 0)
            big_gemm_mfma<<<dim3(MBIG / 128, COUT / 128), 256, 0, stream>>>(
                x, (long)CC * HW, (long)SS * CC * HW, wtx_hl, zx);
        else
            big_gemm_mfma<<<dim3(MBIG / 128, COUT / 128), 256, 0, stream>>>(
                seq, (long)BB * HID * HW, (long)HID * HW, wtx_hl + (long)KH * COUT, zx);

        init_state_kernel<<<(BB * HID * HW) / 256, 256, 0, stream>>>(init_h, init_c, hbuf, cbuf, d);

        const float* wth_d  = wth + (long)d * KH * COUT;
        const float* bias_d = conv_b + d * COUT;
        for (int s = 0; s < SS; ++s) {
            step_gemm_h<<<dim3(MM / 64, COUT / 64, 4), 256, 0, stream>>>(hbuf, wth_d, part);
            lstm_gate_fused<<<(BB * HID * HW) / 256, 256, 0, stream>>>(
                part, zx + (long)s * ZSTEP, bias_d, hbuf, cbuf, seq + (long)s * QSTEP);
        }
    }
    pool_kernel<<<(SS * BB * HID) / 4, 256, 0, stream>>>(seq, pooled);
    head_kernel<<<BB * SS, 128, 0, stream>>>(pooled, fc_w, fc_b, fco_w, fco_b, fca_w, fca_b, out);
}

// Round 7
// 3457.828 us; speedup vs baseline: 1.8828x; 1.3485x over previous
//
#include <hip/hip_runtime.h>

// Problem constants
#define BB 4
#define SS 32
#define CC 128
#define HH 16
#define WW 32
#define HID 128
#define DEPTH 2
#define CIN 256           // CC + HID
#define COUT 512          // 4*HID
#define K9 (CIN * 9)      // 2304
#define KH 1152           // tap-major: k = tap*128 + ch
#define HW (HH * WW)      // 512
#define MM (BB * HW)      // 2048
#define MBIG (SS * BB * HW) // 65536

typedef __attribute__((ext_vector_type(4))) float f32x4;
typedef __attribute__((ext_vector_type(8))) short bf16x8;

static __device__ __forceinline__ unsigned short f2bf(float f) {
    union { float f; unsigned u; } v; v.f = f;
    unsigned r = v.u + 0x7FFF + ((v.u >> 16) & 1);   // RNE
    return (unsigned short)(r >> 16);
}
static __device__ __forceinline__ float bf2f(unsigned short h) {
    union { float f; unsigned u; } v; v.u = ((unsigned)h) << 16; return v.f;
}
static __device__ __forceinline__ unsigned packhl(float f) {
    unsigned short hi = f2bf(f);
    unsigned short lo = f2bf(f - bf2f(hi));
    return (unsigned)hi | ((unsigned)lo << 16);
}

// ---------------------------------------------------------------------------
// Weight split+transpose (tap-major k), both packed bf16 hi|lo:
//   conv_w [DEPTH][COUT][CIN][3][3] ->
//     wtx_hl [DEPTH][KH][COUT]  (cin <  CC : k = tap*CC  + cin)
//     wth_hl [DEPTH][KH][COUT]  (cin >= CC : k = tap*HID + (cin-CC))
// ---------------------------------------------------------------------------
__global__ void transpose_w_kernel(const float* __restrict__ w,
                                   unsigned* __restrict__ wtx_hl,
                                   unsigned* __restrict__ wth_hl) {
    int idx = blockIdx.x * 256 + threadIdx.x;
    if (idx >= DEPTH * K9 * COUT) return;
    int n = idx % COUT;
    int k = (idx / COUT) % K9;
    int d = idx / (COUT * K9);
    int cin = k / 9, tap = k % 9;
    float v = w[(((long)(d * COUT + n) * CIN + cin) * 9) + tap];
    unsigned p = packhl(v);
    if (cin < CC) wtx_hl[((long)d * KH + (tap * CC + cin)) * COUT + n] = p;
    else          wth_hl[((long)d * KH + (tap * HID + (cin - CC))) * COUT + n] = p;
}

// ---------------------------------------------------------------------------
// Broadcast init_h/init_c[d] into packed-h / fp32-c state buffers
// ---------------------------------------------------------------------------
__global__ void init_state_kernel(const float* __restrict__ ih, const float* __restrict__ ic,
                                  unsigned* __restrict__ hhl, float* __restrict__ c, int d) {
    int idx = blockIdx.x * 256 + threadIdx.x;   // B*HID*HW = 262144
    int hid = (idx >> 9) & (HID - 1);
    hhl[idx] = packhl(ih[d * HID + hid]);
    c[idx] = ic[d * HID + hid];
}

// ---------------------------------------------------------------------------
// Big feed-forward GEMM over ALL timesteps — MFMA bf16x3 (hi/lo split).
// Tile 128x128, 4 waves (2x2 of 64x64), BK=32 tap-major.
// HL=0: fp32 input (layer 1, converts in staging); HL=1: packed hi|lo input.
// grid = (512, 4), 256 threads.
// ---------------------------------------------------------------------------
template<int HL>
__launch_bounds__(256)
__global__ void big_gemm_mfma(const void* __restrict__ xin_, long strideS, long strideB,
                              const unsigned* __restrict__ wt_hl,  // [KH][COUT]
                              float* __restrict__ zx) {
    __shared__ unsigned short Ah[128][36], Al[128][36];
    __shared__ unsigned short Bh[128][36], Bl[128][36];

    const int m0 = blockIdx.x * 128;
    const int n0 = blockIdx.y * 128;
    const int tid  = threadIdx.x;
    const int lane = tid & 63;
    const int wid  = tid >> 6;          // 4 waves
    const int wm = (wid >> 1) * 64;     // wave m offset in tile
    const int wn = (wid & 1) * 64;      // wave n offset
    const int sb  = m0 >> 9;            // image index
    const int hw0 = m0 & 511;
    const long imgoff = (long)(sb >> 2) * strideS + (long)(sb & 3) * strideB;
    const float*    imgf = (const float*)xin_ + imgoff;
    const unsigned* imgu = (const unsigned*)xin_ + imgoff;

    f32x4 acc[4][4];
    #pragma unroll
    for (int i = 0; i < 4; ++i)
        #pragma unroll
        for (int j = 0; j < 4; ++j)
            acc[i][j] = (f32x4){0.f, 0.f, 0.f, 0.f};

    for (int k0 = 0; k0 < KH; k0 += 32) {
        const int tap = k0 >> 7;            // uniform per chunk
        const int c0  = k0 & 127;
        const int ky  = tap / 3 - 1;
        const int kx  = tap - (tap / 3) * 3 - 1;
        // --- stage A (im2col gather) ---
        #pragma unroll
        for (int i = 0; i < 16; ++i) {
            int idx = i * 256 + tid;        // 0..4095
            int kk = idx >> 7;              // 0..31
            int m  = idx & 127;
            int hw = hw0 + m;
            int yy = (hw >> 5) + ky;
            int xq = (hw & 31) + kx;
            bool ok = (unsigned)yy < (unsigned)HH && (unsigned)xq < (unsigned)WW;
            if constexpr (HL) {
                unsigned p = ok ? imgu[(c0 + kk) * HW + yy * WW + xq] : 0u;
                Ah[m][kk] = (unsigned short)p;
                Al[m][kk] = (unsigned short)(p >> 16);
            } else {
                float v = ok ? imgf[(c0 + kk) * HW + yy * WW + xq] : 0.f;
                unsigned short h = f2bf(v);
                Ah[m][kk] = h;
                Al[m][kk] = f2bf(v - bf2f(h));
            }
        }
        // --- stage B: packed hi|lo, coalesced ---
        #pragma unroll
        for (int i = 0; i < 16; ++i) {
            int idx = i * 256 + tid;
            int kk = idx >> 7;
            int n  = idx & 127;
            unsigned p = wt_hl[(long)(k0 + kk) * COUT + n0 + n];
            Bh[n][kk] = (unsigned short)p;
            Bl[n][kk] = (unsigned short)(p >> 16);
        }
        __syncthreads();

        const int fr = lane & 15;
        const int kq = (lane >> 4) * 8;
        bf16x8 ah[4], al[4], bh[4], bl[4];
        #pragma unroll
        for (int f = 0; f < 4; ++f) {
            ah[f] = *(const bf16x8*)&Ah[wm + f * 16 + fr][kq];
            al[f] = *(const bf16x8*)&Al[wm + f * 16 + fr][kq];
            bh[f] = *(const bf16x8*)&Bh[wn + f * 16 + fr][kq];
            bl[f] = *(const bf16x8*)&Bl[wn + f * 16 + fr][kq];
        }
        #pragma unroll
        for (int fm = 0; fm < 4; ++fm)
            #pragma unroll
            for (int fn = 0; fn < 4; ++fn) {
                acc[fm][fn] = __builtin_amdgcn_mfma_f32_16x16x32_bf16(ah[fm], bh[fn], acc[fm][fn], 0, 0, 0);
                acc[fm][fn] = __builtin_amdgcn_mfma_f32_16x16x32_bf16(ah[fm], bl[fn], acc[fm][fn], 0, 0, 0);
                acc[fm][fn] = __builtin_amdgcn_mfma_f32_16x16x32_bf16(al[fm], bh[fn], acc[fm][fn], 0, 0, 0);
            }
        __syncthreads();
    }

    const long outbase = (long)sb * COUT * HW;
    const int rm = (lane >> 4) * 4;
    const int cn = lane & 15;
    #pragma unroll
    for (int fm = 0; fm < 4; ++fm)
        #pragma unroll
        for (int fn = 0; fn < 4; ++fn) {
            int m = hw0 + wm + fm * 16 + rm;
            int n = n0 + wn + fn * 16 + cn;
            *(float4*)&zx[outbase + (long)n * HW + m] = *(float4*)&acc[fm][fn];
        }
}

// ---------------------------------------------------------------------------
// Per-step recurrent GEMM — MFMA bf16x3, h input packed hi|lo.
// K=1152 tap-major, split-K=4 (288 each). Tile 64x64, 4 waves (2x2 of 32x32).
// grid = (32, 8, 4) = 1024 wgs, 256 threads.
// ---------------------------------------------------------------------------
__launch_bounds__(256)
__global__ void step_gemm_mfma(const unsigned* __restrict__ hhl,     // [B][HID][HW]
                               const unsigned* __restrict__ wth_hl,  // [KH][COUT]
                               float* __restrict__ part) {
    __shared__ unsigned short Ah[64][36], Al[64][36];
    __shared__ unsigned short Bh[64][36], Bl[64][36];

    const int m0 = blockIdx.x * 64;
    const int n0 = blockIdx.y * 64;
    const int kc = blockIdx.z;
    const int tid  = threadIdx.x;
    const int lane = tid & 63;
    const int wid  = tid >> 6;
    const int wm = (wid >> 1) * 32;
    const int wn = (wid & 1) * 32;
    const int b   = m0 >> 9;
    const int hw0 = m0 & 511;

    f32x4 acc[2][2];
    #pragma unroll
    for (int i = 0; i < 2; ++i)
        #pragma unroll
        for (int j = 0; j < 2; ++j)
            acc[i][j] = (f32x4){0.f, 0.f, 0.f, 0.f};

    for (int k0i = 0; k0i < 288; k0i += 32) {
        const int k0  = kc * 288 + k0i;     // 32-aligned -> single tap
        const int tap = k0 >> 7;
        const int c0  = k0 & 127;
        const int ky  = tap / 3 - 1;
        const int kx  = tap - (tap / 3) * 3 - 1;
        #pragma unroll
        for (int i = 0; i < 8; ++i) {
            int idx = i * 256 + tid;        // 0..2047
            int kk = idx >> 6;              // 0..31
            int m  = idx & 63;
            int hw = hw0 + m;
            int yy = (hw >> 5) + ky;
            int xq = (hw & 31) + kx;
            bool ok = (unsigned)yy < (unsigned)HH && (unsigned)xq < (unsigned)WW;
            unsigned p = ok ? hhl[((long)(b * HID + c0 + kk)) * HW + yy * WW + xq] : 0u;
            Ah[m][kk] = (unsigned short)p;
            Al[m][kk] = (unsigned short)(p >> 16);
        }
        #pragma unroll
        for (int i = 0; i < 8; ++i) {
            int idx = i * 256 + tid;
            int kk = idx >> 6;
            int n  = idx & 63;
            unsigned p = wth_hl[(long)(k0 + kk) * COUT + n0 + n];
            Bh[n][kk] = (unsigned short)p;
            Bl[n][kk] = (unsigned short)(p >> 16);
        }
        __syncthreads();

        const int fr = lane & 15;
        const int kq = (lane >> 4) * 8;
        bf16x8 ah[2], al[2], bh[2], bl[2];
        #pragma unroll
        for (int f = 0; f < 2; ++f) {
            ah[f] = *(const bf16x8*)&Ah[wm + f * 16 + fr][kq];
            al[f] = *(const bf16x8*)&Al[wm + f * 16 + fr][kq];
            bh[f] = *(const bf16x8*)&Bh[wn + f * 16 + fr][kq];
            bl[f] = *(const bf16x8*)&Bl[wn + f * 16 + fr][kq];
        }
        #pragma unroll
        for (int fm = 0; fm < 2; ++fm)
            #pragma unroll
            for (int fn = 0; fn < 2; ++fn) {
                acc[fm][fn] = __builtin_amdgcn_mfma_f32_16x16x32_bf16(ah[fm], bh[fn], acc[fm][fn], 0, 0, 0);
                acc[fm][fn] = __builtin_amdgcn_mfma_f32_16x16x32_bf16(ah[fm], bl[fn], acc[fm][fn], 0, 0, 0);
                acc[fm][fn] = __builtin_amdgcn_mfma_f32_16x16x32_bf16(al[fm], bh[fn], acc[fm][fn], 0, 0, 0);
            }
        __syncthreads();
    }

    const long pbase = (long)kc * BB * COUT * HW;
    const int rm = (lane >> 4) * 4;
    const int cn = lane & 15;
    #pragma unroll
    for (int fm = 0; fm < 2; ++fm)
        #pragma unroll
        for (int fn = 0; fn < 2; ++fn) {
            int m = hw0 + wm + fm * 16 + rm;
            int n = n0 + wn + fn * 16 + cn;
            *(float4*)&part[pbase + ((long)b * COUT + n) * HW + m] = *(float4*)&acc[fm][fn];
        }
}

// ---------------------------------------------------------------------------
// Fused split-K reduce + zx + bias + LSTM cell update; emits packed h.
// ---------------------------------------------------------------------------
__global__ void lstm_gate_fused(const float* __restrict__ part,  // [4][B][COUT][HW]
                                const float* __restrict__ zx,    // [B][COUT][HW] (step slice)
                                const float* __restrict__ bias,  // [COUT]
                                unsigned* __restrict__ hhl, float* __restrict__ c,
                                unsigned* __restrict__ seq_hl) {
    const long PSTR = (long)BB * COUT * HW;
    int idx = blockIdx.x * 256 + threadIdx.x;     // over B*HID*HW = 262144
    int hw  = idx & 511;
    int hid = (idx >> 9) & (HID - 1);
    int b   = idx >> 16;
    long base = (long)b * COUT * HW + hw;
    float g[4];
    #pragma unroll
    for (int gi = 0; gi < 4; ++gi) {
        long o = base + (long)(hid + gi * HID) * HW;
        float v = zx[o] + bias[hid + gi * HID];
        v += part[o];
        v += part[o + PSTR];
        v += part[o + 2 * PSTR];
        v += part[o + 3 * PSTR];
        g[gi] = v;
    }
    float si = 1.f / (1.f + expf(-g[0]));
    float sf = 1.f / (1.f + expf(-g[1]));
    float so = 1.f / (1.f + expf(-g[3]));
    float cs = sf * c[idx] + si * tanhf(g[2]);
    float hs = so * tanhf(cs);
    c[idx] = cs;
    unsigned p = packhl(hs);
    hhl[idx] = p;
    seq_hl[idx] = p;
}

// ---------------------------------------------------------------------------
// Mean pool over HW: seq_hl [S][B][HID][HW] packed -> pooled [S*B*HID]
// ---------------------------------------------------------------------------
__global__ void pool_kernel(const unsigned* __restrict__ seq_hl, float* __restrict__ pooled) {
    int row  = blockIdx.x * 4 + (threadIdx.x >> 6);
    int lane = threadIdx.x & 63;
    const unsigned* p = seq_hl + (long)row * HW;
    float sum = 0.f;
    #pragma unroll
    for (int i = 0; i < HW / 64; ++i) {
        unsigned u = p[lane + i * 64];
        sum += bf2f((unsigned short)u) + bf2f((unsigned short)(u >> 16));
    }
    #pragma unroll
    for (int off = 32; off; off >>= 1) sum += __shfl_down(sum, off);
    if (lane == 0) pooled[row] = sum * (1.f / HW);
}

// ---------------------------------------------------------------------------
// FC + ReLU + two scalar heads.
// ---------------------------------------------------------------------------
__global__ void head_kernel(const float* __restrict__ pooled,
                            const float* __restrict__ fc_w, const float* __restrict__ fc_b,
                            const float* __restrict__ fco_w, const float* __restrict__ fco_b,
                            const float* __restrict__ fca_w, const float* __restrict__ fca_b,
                            float* __restrict__ out) {
    int bs = blockIdx.x;          // b*S + s
    int b  = bs / SS;
    int s  = bs % SS;
    int j  = threadIdx.x;
    const float* prow = pooled + (long)(s * BB + b) * HID;
    float acc = fc_b[j];
    #pragma unroll 4
    for (int k = 0; k < HID; ++k) acc += fc_w[j * HID + k] * prow[k];
    float f = fmaxf(acc, 0.f);
    __shared__ float ro[128], ra[128];
    ro[j] = f * fco_w[j];
    ra[j] = f * fca_w[j];
    __syncthreads();
    for (int off = 64; off; off >>= 1) {
        if (j < off) { ro[j] += ro[j + off]; ra[j] += ra[j + off]; }
        __syncthreads();
    }
    if (j == 0) {
        out[bs]           = ro[0] + fco_b[0];
        out[BB * SS + bs] = ra[0] + fca_b[0];
    }
}

// ---------------------------------------------------------------------------
extern "C" void kernel_launch(void* const* d_in, const int* in_sizes, int n_in,
                              void* d_out, int out_size, void* d_ws, size_t ws_size,
                              hipStream_t stream) {
    const float* x      = (const float*)d_in[0];
    const float* conv_w = (const float*)d_in[1];
    const float* conv_b = (const float*)d_in[2];
    const float* init_h = (const float*)d_in[3];
    const float* init_c = (const float*)d_in[4];
    const float* fc_w   = (const float*)d_in[5];
    const float* fc_b   = (const float*)d_in[6];
    const float* fco_w  = (const float*)d_in[7];
    const float* fco_b  = (const float*)d_in[8];
    const float* fca_w  = (const float*)d_in[9];
    const float* fca_b  = (const float*)d_in[10];
    float* out = (float*)d_out;

    // Workspace carve-up (4B units), total 48,977,312 words = 195.9 MB.
    unsigned* wtx_hl = (unsigned*)d_ws;                    // DEPTH*KH*COUT = 1,179,648
    unsigned* wth_hl = wtx_hl + (long)DEPTH * KH * COUT;   // 1,179,648
    float* zx        = (float*)(wth_hl + (long)DEPTH * KH * COUT); // S*B*COUT*HW = 33,554,432
    unsigned* seq_hl = (unsigned*)(zx + (long)SS * BB * COUT * HW); // S*B*HID*HW = 8,388,608
    float* part      = (float*)(seq_hl + (long)SS * BB * HID * HW); // 4*B*COUT*HW = 4,194,304
    unsigned* hhl    = (unsigned*)(part + (long)4 * BB * COUT * HW); // 262,144
    float* cbuf      = (float*)(hhl + (long)BB * HID * HW);          // 262,144
    float* pooled    = cbuf + (long)BB * HID * HW;                   // 16,384

    transpose_w_kernel<<<(DEPTH * K9 * COUT + 255) / 256, 256, 0, stream>>>(conv_w, wtx_hl, wth_hl);

    const long ZSTEP = (long)BB * COUT * HW;
    const long QSTEP = (long)BB * HID * HW;

    for (int d = 0; d < DEPTH; ++d) {
        // x-part of the conv for ALL timesteps: one big parallel MFMA GEMM
        if (d == 0)
            big_gemm_mfma<0><<<dim3(MBIG / 128, COUT / 128), 256, 0, stream>>>(
                x, (long)CC * HW, (long)SS * CC * HW, wtx_hl, zx);
        else
            big_gemm_mfma<1><<<dim3(MBIG / 128, COUT / 128), 256, 0, stream>>>(
                seq_hl, (long)BB * HID * HW, (long)HID * HW, wtx_hl + (long)KH * COUT, zx);

        init_state_kernel<<<(BB * HID * HW) / 256, 256, 0, stream>>>(init_h, init_c, hhl, cbuf, d);

        const unsigned* wth_d = wth_hl + (long)d * KH * COUT;
        const float* bias_d   = conv_b + d * COUT;
        for (int s = 0; s < SS; ++s) {
            step_gemm_mfma<<<dim3(MM / 64, COUT / 64, 4), 256, 0, stream>>>(hhl, wth_d, part);
            lstm_gate_fused<<<(BB * HID * HW) / 256, 256, 0, stream>>>(
                part, zx + (long)s * ZSTEP, bias_d, hhl, cbuf, seq_hl + (long)s * QSTEP);
        }
    }
    pool_kernel<<<(SS * BB * HID) / 4, 256, 0, stream>>>(seq_hl, pooled);
    head_kernel<<<BB * SS, 128, 0, stream>>>(pooled, fc_w, fc_b, fco_w, fco_b, fca_w, fca_b, out);
}